// Round 17
// baseline (613.016 us; speedup 1.0000x reference)
//
#include <hip/hip_runtime.h>
#include <stdint.h>

#define H 512
#define W 512
#define HW (H * W)
#define BATCH 32
#define KS 5
#define NBH 8              // batches per block (grid y = 4); K read ONCE/block
#define NSTEP (KS * NBH)   // 40 steps
#define PD 2               // f-load lookahead (steps) -- kept small for regs

typedef float nf4 __attribute__((ext_vector_type(4)));
typedef __attribute__((address_space(3))) uint32_t lds_u32;
typedef const __attribute__((address_space(1))) uint32_t glb_u32;

// Tap-row-outer / batch-inner, K staged through double-buffered LDS with
// global_load_lds (K never occupies a VGPR in flight). Measured history:
// register-resident K plans spill ~100 regs (VGPR cap is 128 on this
// toolchain regardless of launch-bounds/waves_per_eu: 84/128/128 across
// rounds 12/13/16; sched_barrier no-op => liveness is IR-level, not
// scheduling). This structure fits 128 BY CONSTRUCTION:
//   acc[8][4]=32 + rbuf[2][3]=24 + Kt=20 + fcr=8 + dtb=8 + temps ~ 110.
// LDS 20,480 B -> 8 blocks/CU; VGPR 128-class -> 16 waves/CU; grid 2048
// = 8 blocks/CU exactly: all limits align at ~50% occupancy (vs 19%).
// One barrier per tap-row (5/block); its implicit vmcnt(0) doubles as the
// staging drain. OOB tap-rows: stage clamped rows, skip FMAs (uniform).
__global__ __launch_bounds__(128, 2) void op2d_kernel(
    const float* __restrict__ f,   // (B,H,W)
    const float* __restrict__ K,   // (5,5,H,W)
    const float* __restrict__ dt,  // (B,)
    float* __restrict__ out)       // (B,H,W)
{
    __shared__ float kl[2][KS][W];           // 2 x 5 x 512 floats = 20,480 B

    const int tid  = threadIdx.x;            // 0..127
    const int w0   = tid * 4;                // 0..508
    const int lane = tid & 63;
    const int wv   = tid >> 6;               // wave id 0/1
    const int bx   = blockIdx.x;
    // XCD bands: adjacent rows are 8 block-IDs apart (same XCD) -> f halo
    // L2-local; same-row y-groups are 512 apart (0 mod 8) -> K L2-local.
    const int r    = (bx & 7) * 64 + (bx >> 3);
    const int b0   = blockIdx.y * NBH;

    const bool wl = (w0 >= 4);
    const bool wr = (w0 <= 504);

    // Clamped source-row offsets for the 5 tap-rows (block-uniform).
    int rowoff[KS]; bool inb[KS];
#pragma unroll
    for (int i = 0; i < KS; ++i) {
        const int gr = r + i - 2;
        inb[i] = (gr >= 0) && (gr < H);
        rowoff[i] = (gr < 0 ? 0 : (gr >= H ? H - 1 : gr)) * W;
    }

    // f stream: step s -> tap-row i = s/NBH, batch bi = s%NBH.
    nf4 rbuf[PD][3];
#define FISSUE(s) {                                                          \
        const float* fb = f + (size_t)(b0 + (s) % NBH) * HW                  \
                            + rowoff[(s) / NBH] + w0;                        \
        rbuf[(s) % PD][0] = wl ? *(const nf4*)(fb - 4) : (nf4)0.f;           \
        rbuf[(s) % PD][1] =      *(const nf4*)(fb);                          \
        rbuf[(s) % PD][2] = wr ? *(const nf4*)(fb + 4) : (nf4)0.f;           \
    }

    // Stage K tap-row ti into LDS buffer `buf`: 5 taps x 512 floats. Each
    // wave copies its 1KB half-row per tap: per-lane 16B global source,
    // wave-uniform LDS base + lane*16 dest (the required pattern). Zero
    // VGPR results; completion tracked by vmcnt, drained at the barrier.
#define KSTAGE(ti, buf) {                                                    \
        _Pragma("unroll")                                                    \
        for (int j = 0; j < KS; ++j) {                                       \
            const float* g = K + (size_t)((ti) * KS + j) * HW                \
                               + rowoff[ti] + wv * 256 + lane * 4;           \
            __builtin_amdgcn_global_load_lds(                                \
                (glb_u32*)g, (lds_u32*)&kl[buf][j][wv * 256], 16, 0, 0);     \
        }                                                                    \
    }

    // f prologue first, then tap-row 0 staging.
#pragma unroll
    for (int s = 0; s < PD; ++s) FISSUE(s);
    KSTAGE(0, 0);

    // dt for the 8 batches: two vector loads (b0 is a multiple of 8).
    const nf4 dt0 = *(const nf4*)&dt[b0];
    const nf4 dt1 = *(const nf4*)&dt[b0 + 4];
    const float dtb[NBH] = { dt0.x, dt0.y, dt0.z, dt0.w,
                             dt1.x, dt1.y, dt1.z, dt1.w };

    float acc[NBH][4] = {};   // per-batch df accumulators (32 regs)
    nf4 fcr[2];               // f-center reload ring (2-step lookahead)

    __syncthreads();          // kl[0] ready (implicit vmcnt(0) drain)

#pragma unroll
    for (int i = 0; i < KS; ++i) {
        // Issue next tap-row's staging: in flight across all 8 batch-steps.
        if (i + 1 < KS) KSTAGE(i + 1, (i + 1) & 1);

        // Current tap-row K -> 5 x ds_read_b128 (16B/lane, conflict-free).
        nf4 Kt[KS];
        if (inb[i]) {
#pragma unroll
            for (int j = 0; j < KS; ++j)
                Kt[j] = *(const nf4*)&kl[i & 1][j][w0];
        }

#pragma unroll
        for (int bi = 0; bi < NBH; ++bi) {
            const int s = i * NBH + bi;

            // consume this step's f window, refill the slot PD ahead
            const nf4 ra = rbuf[s % PD][0];
            const nf4 rb = rbuf[s % PD][1];
            const nf4 rc = rbuf[s % PD][2];
            if (s + PD < NSTEP) FISSUE(s + PD);

            // f-center preloads for the first 2 epilogue batches.
            if (i == KS - 2 && bi >= NBH - 2) {
                const int bt = bi - (NBH - 2);
                fcr[bt & 1] = *(const nf4*)(f + (size_t)(b0 + bt) * HW
                                              + (size_t)r * W + w0);
            }

            if (inb[i]) {   // block-uniform; OOB tap-row contributes zero
                const float buf[12] = { ra.x, ra.y, ra.z, ra.w,
                                        rb.x, rb.y, rb.z, rb.w,
                                        rc.x, rc.y, rc.z, rc.w };
#pragma unroll
                for (int j = 0; j < KS; ++j) {
                    acc[bi][0] += Kt[j].x * buf[j + 2];
                    acc[bi][1] += Kt[j].y * buf[j + 3];
                    acc[bi][2] += Kt[j].z * buf[j + 4];
                    acc[bi][3] += Kt[j].w * buf[j + 5];
                }
            }

            // batch bi complete after the last tap-row (always runs, even
            // when tap-row 4 is OOB): store + advance the center ring.
            if (i == KS - 1) {
                const nf4 fc = fcr[bi & 1];
                if (bi + 2 < NBH)
                    fcr[bi & 1] = *(const nf4*)(f + (size_t)(b0 + bi + 2) * HW
                                                  + (size_t)r * W + w0);
                nf4 o;
                o.x = fmaxf(fc.x + acc[bi][0] * dtb[bi], 0.f);
                o.y = fmaxf(fc.y + acc[bi][1] * dtb[bi], 0.f);
                o.z = fmaxf(fc.z + acc[bi][2] * dtb[bi], 0.f);
                o.w = fmaxf(fc.w + acc[bi][3] * dtb[bi], 0.f);
                __builtin_nontemporal_store(o,
                    (nf4*)(out + ((size_t)(b0 + bi) * H + r) * W + w0));
            }
        }

        // Barrier: (a) drains this iter's staging (vmcnt(0) before
        // s_barrier), (b) all reads of kl[i&1] done before iter i+1's
        // KSTAGE overwrites it. 5 barriers per block total.
        if (i + 1 < KS) __syncthreads();
    }
#undef FISSUE
#undef KSTAGE
}

extern "C" void kernel_launch(void* const* d_in, const int* in_sizes, int n_in,
                              void* d_out, int out_size, void* d_ws, size_t ws_size,
                              hipStream_t stream) {
    const float* f  = (const float*)d_in[0];   // (32,512,512)
    const float* K  = (const float*)d_in[1];   // (5,5,512,512)
    const float* dt = (const float*)d_in[2];   // (32,)
    float* out = (float*)d_out;

    dim3 block(128);
    dim3 grid(H, BATCH / NBH);   // 512 rows x 4 batch-groups = 2048 blocks
    op2d_kernel<<<grid, block, 0, stream>>>(f, K, dt, out);
}

// Round 19
// 137.347 us; speedup vs baseline: 4.4633x; 4.4633x over previous
//
#include <hip/hip_runtime.h>

#define H 512
#define W 512
#define HW (H * W)
#define BATCH 32
#define KS 5
#define NBH 8              // batches per block; K loaded once, reused 8x

typedef float nf2 __attribute__((ext_vector_type(2)));

// Thread = TWO output cols (float2) of ONE row r, NBH batches serially.
// Register plan (the binding constraint, measured rounds 12-17: arch-VGPR
// cap is 128 on this toolchain; anything above spills to scratch):
//   Kt 25 x nf2 = 50  (loaded once per block, zero inner-loop K traffic)
//   win[2][5][3] nf2 = 60  (double-buffered f window; next batch's 15
//                           8B-loads fly under the current 50 FMAs)
//   acc 2 + temps ~10  => ~122 < 128. No AGPR parking, no scratch.
// f-center for the epilogue = win row 2 middle element (free).
// Block 256 (one row), grid 512 x 4 = 2048 blocks; ~125 VGPR -> 4 waves/
// SIMD -> ~50% occupancy (round 2 ran at 16%, latency-exposed, 60us).
// Same-row batch-groups are 512 block-IDs apart -> same XCD -> K L2-local.
// OOB tap-rows: zero the K taps, clamp the f row address (garbage * 0).
// OOB cols: wl/wr zero the window edge nf2s.
// NO LDS, NO BARRIERS.
__global__ __launch_bounds__(256, 1) void op2d_kernel(
    const float* __restrict__ f,   // (B,H,W)
    const float* __restrict__ K,   // (5,5,H,W)
    const float* __restrict__ dt,  // (B,)
    float* __restrict__ out)       // (B,H,W)
{
    const int tid = threadIdx.x;          // 0..255
    const int c0  = tid * 2;              // 0..510
    const int r   = blockIdx.x;           // output row (block-uniform)
    const int b0  = blockIdx.y * NBH;

    const bool wl = (c0 >= 2);            // left halo nf2 in bounds
    const bool wr = (c0 <= 508);          // right halo nf2 in bounds

    // Clamped tap-row offsets (block-uniform -> SGPRs).
    int rowoff[KS]; bool inb[KS];
#pragma unroll
    for (int i = 0; i < KS; ++i) {
        const int gr = r + i - 2;
        inb[i] = (gr >= 0) && (gr < H);
        rowoff[i] = (gr < 0 ? 0 : (gr >= H ? H - 1 : gr)) * W;
    }

    // Load one f-window row (cols c0-2 .. c0+3 as 3 x nf2) for batch b.
    nf2 win[2][KS][3];
#define FROW(b, i, d) {                                                      \
        const float* fp = f + (size_t)(b0 + (b)) * HW + rowoff[i] + c0;      \
        (d)[0] = wl ? *(const nf2*)(fp - 2) : (nf2)0.f;                      \
        (d)[1] =      *(const nf2*)(fp);                                     \
        (d)[2] = wr ? *(const nf2*)(fp + 2) : (nf2)0.f;                      \
    }

    // Prologue: batch 0's window first (head of the VMEM queue)...
#pragma unroll
    for (int i = 0; i < KS; ++i) FROW(0, i, win[0][i]);

    // ...then the 25 K taps (block-lifetime registers). OOB tap-rows -> 0.
    nf2 Kt[KS][KS];
#pragma unroll
    for (int i = 0; i < KS; ++i) {
#pragma unroll
        for (int j = 0; j < KS; ++j)
            Kt[i][j] = inb[i]
                ? *(const nf2*)(K + (size_t)(i * KS + j) * HW
                                  + (size_t)r * W + c0)
                : (nf2)0.f;
    }

#pragma unroll
    for (int b = 0; b < NBH; ++b) {
        // Issue next batch's 15 window loads; they land under this
        // batch's 50 FMAs (+ the following iteration's issue slots).
        if (b + 1 < NBH) {
#pragma unroll
            for (int i = 0; i < KS; ++i) FROW(b + 1, i, win[(b + 1) & 1][i]);
        }

        const float dtv = dt[b0 + b];     // uniform -> scalar load

        float ax = 0.f, ay = 0.f;
#pragma unroll
        for (int i = 0; i < KS; ++i) {
            const nf2 e0 = win[b & 1][i][0];
            const nf2 e1 = win[b & 1][i][1];
            const nf2 e2 = win[b & 1][i][2];
            const float w[6] = { e0.x, e0.y, e1.x, e1.y, e2.x, e2.y };
            // out col c0   uses f cols c0+j-2 -> w[j]
            // out col c0+1 uses f cols c0+j-1 -> w[j+1]
#pragma unroll
            for (int j = 0; j < KS; ++j) {
                ax += Kt[i][j].x * w[j];
                ay += Kt[i][j].y * w[j + 1];
            }
        }

        // f-center = window row 2, middle nf2 (free).
        const nf2 fc = win[b & 1][2][1];
        nf2 o;
        o.x = fmaxf(fc.x + ax * dtv, 0.f);
        o.y = fmaxf(fc.y + ay * dtv, 0.f);
        __builtin_nontemporal_store(o,
            (nf2*)(out + ((size_t)(b0 + b) * H + r) * W + c0));
    }
#undef FROW
}

extern "C" void kernel_launch(void* const* d_in, const int* in_sizes, int n_in,
                              void* d_out, int out_size, void* d_ws, size_t ws_size,
                              hipStream_t stream) {
    const float* f  = (const float*)d_in[0];   // (32,512,512)
    const float* K  = (const float*)d_in[1];   // (5,5,512,512)
    const float* dt = (const float*)d_in[2];   // (32,)
    float* out = (float*)d_out;

    dim3 block(256);
    dim3 grid(H, BATCH / NBH);   // 512 rows x 4 batch-groups = 2048 blocks
    op2d_kernel<<<grid, block, 0, stream>>>(f, K, dt, out);
}

// Round 20
// 116.756 us; speedup vs baseline: 5.2504x; 1.1764x over previous
//
#include <hip/hip_runtime.h>
#include <stdint.h>

#define H 512
#define W 512
#define HW (H * W)
#define BATCH 32
#define KS 5
#define NBH 8              // batches per block; K loaded once, reused 8x
#define WPAD 516           // padded LDS row (right halo reads stay in-array)

typedef float nf2 __attribute__((ext_vector_type(2)));
typedef __attribute__((address_space(3))) uint32_t lds_u32;
typedef const __attribute__((address_space(1))) uint32_t glb_u32;

// Thread = 2 output cols of row r, 8 batches serially. Round-19 measured:
// Kt stays register-resident (VGPR=68 = Kt50 + temps, WRITE exactly 32MB)
// but the compiler SINKS register-prefetched f loads to their uses,
// destroying the software pipeline (VALUBusy 19%, 60us latency-bound).
// Fix: f goes through double-buffered LDS via global_load_lds -- no VGPR
// result, so the allocator CANNOT sink it. Stage(b+1) issues before
// compute(b); the end-of-batch barrier's implicit vmcnt(0) is the drain
// => a full compute phase of latency cover, enforced structurally.
// XCD swizzle: adjacent rows + all batch-groups of a row on one XCD ->
// f halo and K rows L2-local (round 19 FETCH=121MB was ~2x f over-fetch).
// Registers: Kt 50 + ds-results ~12 + addr/acc ~25 ~= 90 < 128 cap.
// LDS 20,640B -> 7 blocks/CU; ~90 VGPR -> 5 waves/SIMD.
__global__ __launch_bounds__(256, 1) void op2d_kernel(
    const float* __restrict__ f,   // (B,H,W)
    const float* __restrict__ K,   // (5,5,H,W)
    const float* __restrict__ dt,  // (B,)
    float* __restrict__ out)       // (B,H,W)
{
    __shared__ float fl[2][KS][WPAD];        // 20,640 B

    const int tid  = threadIdx.x;            // 0..255
    const int c0   = tid * 2;                // 0..510
    const int lane = tid & 63;
    const int wv   = tid >> 6;               // wave 0..3
    const int bx   = blockIdx.x;
    const int r    = (bx & 7) * 64 + (bx >> 3);  // XCD-contiguous row bands
    const int b0   = blockIdx.y * NBH;

    const bool wl = (c0 >= 2);
    const bool wr = (c0 <= 508);
    const int  cl = wl ? c0 - 2 : 0;         // clamped left-halo index

    // Clamped tap-row offsets (block-uniform).
    int rowoff[KS]; bool inb[KS];
#pragma unroll
    for (int i = 0; i < KS; ++i) {
        const int gr = r + i - 2;
        inb[i] = (gr >= 0) && (gr < H);
        rowoff[i] = (gr < 0 ? 0 : (gr >= H ? H - 1 : gr)) * W;
    }

    // Stage batch b's 5 f-rows (clamped) into LDS buffer `buf`.
    // 10 half-row chunks (1KB each = 64 lanes x 16B), round-robin over the
    // 4 waves (wave-uniform branch). No VGPR results -> un-sinkable.
#define STAGE(b, buf) {                                                      \
        _Pragma("unroll")                                                    \
        for (int c = 0; c < 10; ++c) {                                       \
            if ((c & 3) == wv) {                                             \
                const int row = c >> 1, half = c & 1;                        \
                const float* g = f + (size_t)(b0 + (b)) * HW                 \
                                   + rowoff[row] + half * 256 + lane * 4;    \
                __builtin_amdgcn_global_load_lds((glb_u32*)g,                \
                    (lds_u32*)&fl[buf][row][half * 256], 16, 0, 0);          \
            }                                                                \
        }                                                                    \
    }

    STAGE(0, 0);   // batch 0 in flight during Kt loads

    // 25 K taps, block-lifetime registers (proven resident in round 19).
    // OOB tap-rows -> zero taps (zero-padding; staged clamped row * 0 = 0).
    nf2 Kt[KS][KS];
#pragma unroll
    for (int i = 0; i < KS; ++i)
#pragma unroll
        for (int j = 0; j < KS; ++j)
            Kt[i][j] = inb[i]
                ? *(const nf2*)(K + (size_t)(i * KS + j) * HW
                                  + (size_t)r * W + c0)
                : (nf2)0.f;

    __syncthreads();   // vmcnt(0): fl[0] ready (Kt loads drained too)

#pragma unroll
    for (int b = 0; b < NBH; ++b) {
        // Next batch's staging flies under this batch's compute.
        if (b + 1 < NBH) STAGE(b + 1, (b + 1) & 1);

        const float dtv = dt[b0 + b];        // uniform -> scalar load

        float ax = 0.f, ay = 0.f;
        nf2 fc;
#pragma unroll
        for (int i = 0; i < KS; ++i) {
            // 3 x ds_read_b64; stride-2 lanes = 2-way bank alias (free).
            nf2 e0 = *(const nf2*)&fl[b & 1][i][cl];
            nf2 e1 = *(const nf2*)&fl[b & 1][i][c0];
            nf2 e2 = *(const nf2*)&fl[b & 1][i][c0 + 2];  // pad keeps in-array
            e0 = wl ? e0 : (nf2)0.f;
            e2 = wr ? e2 : (nf2)0.f;
            if (i == 2) fc = e1;             // f-center: free
            const float w[6] = { e0.x, e0.y, e1.x, e1.y, e2.x, e2.y };
            // out col c0 uses w[j]; out col c0+1 uses w[j+1]
#pragma unroll
            for (int j = 0; j < KS; ++j) {
                ax += Kt[i][j].x * w[j];
                ay += Kt[i][j].y * w[j + 1];
            }
        }

        nf2 o;
        o.x = fmaxf(fc.x + ax * dtv, 0.f);
        o.y = fmaxf(fc.y + ay * dtv, 0.f);
        __builtin_nontemporal_store(o,
            (nf2*)(out + ((size_t)(b0 + b) * H + r) * W + c0));

        // Drain stage(b+1) (implicit vmcnt(0)) + protect fl[b&1] from
        // being overwritten by stage(b+2) before all waves finished it.
        if (b + 1 < NBH) __syncthreads();
    }
#undef STAGE
}

extern "C" void kernel_launch(void* const* d_in, const int* in_sizes, int n_in,
                              void* d_out, int out_size, void* d_ws, size_t ws_size,
                              hipStream_t stream) {
    const float* f  = (const float*)d_in[0];   // (32,512,512)
    const float* K  = (const float*)d_in[1];   // (5,5,512,512)
    const float* dt = (const float*)d_in[2];   // (32,)
    float* out = (float*)d_out;

    dim3 block(256);
    dim3 grid(H, BATCH / NBH);   // 512 rows x 4 batch-groups = 2048 blocks
    op2d_kernel<<<grid, block, 0, stream>>>(f, K, dt, out);
}

// Round 23
// 115.913 us; speedup vs baseline: 5.2886x; 1.0073x over previous
//
#include <hip/hip_runtime.h>
#include <stdint.h>

#define H 512
#define W 512
#define HW (H * W)
#define BATCH 32
#define KS 5
#define NBH 8              // batches per block; K loaded once, reused 8x
#define WPAD 516           // padded LDS row; 516*4=2064B, 16B-multiple
#define NBUF 3             // 3 buffers: compute b | b+1 landing | b+2 landing

typedef float nf2 __attribute__((ext_vector_type(2)));
typedef __attribute__((address_space(3))) uint32_t lds_u32;
typedef const __attribute__((address_space(1))) uint32_t glb_u32;

// Round-20 measured (harness 116.8us, kernel ~40us est): LDS-staged f via
// global_load_lds fixed the load-sinking problem (no spill, WRITE exactly
// 32MB). Residual theory: per-batch __syncthreads() vmcnt(0) drain gives
// stage(b+1) only ONE compute phase (~300cyc) of cover vs ~900cyc HBM miss.
// This round: T3/T4 port -- 3 LDS buffers, stage TWO batches ahead, and
// replace the full drain with per-wave COUNTED vmcnt + raw s_barrier:
//   wave issue per iter: [stage(b+2): N_w chunks] ... [store(b): 1]
//   wait vmcnt(N_w+1) => stage(b+1) (and older stores) complete; the
//   N_w newest (stage b+2) + store stay in flight across the barrier.
// N_w by construction: waves 0,1 = 3 chunks, waves 2,3 = 2 (c&3)==wv.
// Epilogue b=6: no stage(8) -> vmcnt(1). Over-waiting is safe-direction.
// sched_barrier(0) after each barrier pins the schedule (rule 18/m201).
// Kt register-resident (proven r19: VGPR=68), thread=2 cols, XCD swizzle.
// LDS 30,960B -> 5 blocks/CU -> 20 waves/CU.
__global__ __launch_bounds__(256, 1) void op2d_kernel(
    const float* __restrict__ f,   // (B,H,W)
    const float* __restrict__ K,   // (5,5,H,W)
    const float* __restrict__ dt,  // (B,)
    float* __restrict__ out)       // (B,H,W)
{
    __shared__ float fl[NBUF][KS][WPAD];     // 30,960 B

    const int tid  = threadIdx.x;            // 0..255
    const int c0   = tid * 2;                // 0..510
    const int lane = tid & 63;
    const int wv   = tid >> 6;               // wave 0..3 (wave-uniform)
    const int bx   = blockIdx.x;
    const int r    = (bx & 7) * 64 + (bx >> 3);  // XCD-contiguous row bands
    const int b0   = blockIdx.y * NBH;

    const bool wl = (c0 >= 2);
    const bool wr = (c0 <= 508);
    const int  cl = wl ? c0 - 2 : 0;         // clamped left-halo index

    // Clamped tap-row offsets (block-uniform).
    int rowoff[KS]; bool inb[KS];
#pragma unroll
    for (int i = 0; i < KS; ++i) {
        const int gr = r + i - 2;
        inb[i] = (gr >= 0) && (gr < H);
        rowoff[i] = (gr < 0 ? 0 : (gr >= H ? H - 1 : gr)) * W;
    }

    // Stage batch b's 5 f-rows into LDS buffer `buf`: 10 x 1KB chunks
    // (64 lanes x 16B), round-robin over waves. No VGPR results.
#define STAGE(b, buf) {                                                      \
        _Pragma("unroll")                                                    \
        for (int c = 0; c < 10; ++c) {                                       \
            if ((c & 3) == wv) {                                             \
                const int row = c >> 1, half = c & 1;                        \
                const float* g = f + (size_t)(b0 + (b)) * HW                 \
                                   + rowoff[row] + half * 256 + lane * 4;    \
                __builtin_amdgcn_global_load_lds((glb_u32*)g,                \
                    (lds_u32*)&fl[buf][row][half * 256], 16, 0, 0);          \
            }                                                                \
        }                                                                    \
    }

    STAGE(0, 0);
    STAGE(1, 1);

    // 25 K taps, block-lifetime registers. OOB tap-rows -> zero taps.
    nf2 Kt[KS][KS];
#pragma unroll
    for (int i = 0; i < KS; ++i)
#pragma unroll
        for (int j = 0; j < KS; ++j)
            Kt[i][j] = inb[i]
                ? *(const nf2*)(K + (size_t)(i * KS + j) * HW
                                  + (size_t)r * W + c0)
                : (nf2)0.f;

    __syncthreads();   // one-time full drain: fl[0], fl[1], Kt all ready

#pragma unroll
    for (int b = 0; b < NBH; ++b) {
        // 2-deep: this lands two compute phases + a barrier from now.
        if (b + 2 < NBH) STAGE(b + 2, (b + 2) % NBUF);

        const float dtv = dt[b0 + b];        // uniform -> scalar load

        float ax = 0.f, ay = 0.f;
        nf2 fc;
#pragma unroll
        for (int i = 0; i < KS; ++i) {
            // 3 x ds_read_b64; stride-2 lanes = 2-way bank alias (free).
            nf2 e0 = *(const nf2*)&fl[b % NBUF][i][cl];
            nf2 e1 = *(const nf2*)&fl[b % NBUF][i][c0];
            nf2 e2 = *(const nf2*)&fl[b % NBUF][i][c0 + 2];
            e0 = wl ? e0 : (nf2)0.f;
            e2 = wr ? e2 : (nf2)0.f;
            if (i == 2) fc = e1;             // f-center: free
            const float w[6] = { e0.x, e0.y, e1.x, e1.y, e2.x, e2.y };
#pragma unroll
            for (int j = 0; j < KS; ++j) {
                ax += Kt[i][j].x * w[j];     // out col c0
                ay += Kt[i][j].y * w[j + 1]; // out col c0+1
            }
        }

        nf2 o;
        o.x = fmaxf(fc.x + ax * dtv, 0.f);
        o.y = fmaxf(fc.y + ay * dtv, 0.f);
        __builtin_nontemporal_store(o,
            (nf2*)(out + ((size_t)(b0 + b) * H + r) * W + c0));

        // Counted drain (NOT vmcnt(0)): wait only until stage(b+1) is
        // complete; stage(b+2)'s chunks + this store stay in flight
        // across the barrier. Buffer-recycle safety: stage(b+3) (issued
        // next iter, same buffer as compute(b)) is gated by this barrier.
        if (b + 1 < NBH) {
            if (b + 2 < NBH) {
                if (wv < 2) asm volatile("s_waitcnt vmcnt(4)" ::: "memory");
                else        asm volatile("s_waitcnt vmcnt(3)" ::: "memory");
            } else {       // b == 6: only stage(7) + stores outstanding
                asm volatile("s_waitcnt vmcnt(1)" ::: "memory");
            }
            __builtin_amdgcn_s_barrier();
            __builtin_amdgcn_sched_barrier(0);   // pin: nothing crosses
        }
    }
#undef STAGE
}

extern "C" void kernel_launch(void* const* d_in, const int* in_sizes, int n_in,
                              void* d_out, int out_size, void* d_ws, size_t ws_size,
                              hipStream_t stream) {
    const float* f  = (const float*)d_in[0];   // (32,512,512)
    const float* K  = (const float*)d_in[1];   // (5,5,512,512)
    const float* dt = (const float*)d_in[2];   // (32,)
    float* out = (float*)d_out;

    dim3 block(256);
    dim3 grid(H, BATCH / NBH);   // 512 rows x 4 batch-groups = 2048 blocks
    op2d_kernel<<<grid, block, 0, stream>>>(f, K, dt, out);
}